// Round 1
// baseline (553.646 us; speedup 1.0000x reference)
//
#include <hip/hip_runtime.h>

// cAttention: B=8, C=16, L=512, D=256, all fp32.
// Decomposition:
//   prep:   Wcomb = Wout @ Wv (256x256), bcomb = Wout @ bv
//   qk:     GEMM (65536 x 512) = xf @ [Wq;Wk]^T + bias (bh folded into q)
//   score:  per position p (16 channels): s[q,k] = sum_d Vw[d]*tanh(q+k),
//           a[p,c] = softmax diag only
//   out:    GEMM (65536 x 256) = xf @ Wcomb^T, epilogue a*(y+bcomb)+bout,
//           written back in (B,C,L,D) layout.

#define BM 64
#define BN 64
#define BK 16
#define LDA (BM + 4)  // pad +4 floats: keeps float4 alignment, 2-way max bank aliasing (free)

__device__ __forceinline__ float tanh_fast(float x) {
  // tanh via exp; clamp so exp never overflows. tanh(|x|>=10) rounds to +-1 in fp32.
  x = fminf(10.f, fmaxf(-10.f, x));
  const float e2 = __expf(2.f * x);
  return (e2 - 1.f) * __builtin_amdgcn_rcpf(e2 + 1.f);
}

__global__ __launch_bounds__(256) void ca_prep_kernel(
    const float* __restrict__ Wqkv, const float* __restrict__ Wout,
    const float* __restrict__ bqkv,
    float* __restrict__ Wcomb, float* __restrict__ bcomb) {
  const int dp = blockIdx.x;   // output row of Wcomb
  const int e = threadIdx.x;   // output col
  const float* wrow = Wout + (size_t)dp * 256;
  float acc = 0.f;
  for (int f = 0; f < 256; ++f)
    acc = fmaf(wrow[f], Wqkv[(size_t)(512 + f) * 256 + e], acc);
  Wcomb[(size_t)dp * 256 + e] = acc;
  if (e == 0) {
    float b = 0.f;
    for (int f = 0; f < 256; ++f) b = fmaf(wrow[f], bqkv[512 + f], b);
    bcomb[dp] = b;
  }
}

// ---- QK GEMM: C[r, n] = sum_e xf[r, e] * Wqkv[n, e] + bias, n in [0,512) ----
// xf row r -> x[b, c, l, :] with c = r&15, p = r>>4, l = p&511, b = p>>9.
__global__ __launch_bounds__(256) void ca_qk_gemm_kernel(
    const float* __restrict__ x, const float* __restrict__ Wqkv,
    const float* __restrict__ bqkv, const float* __restrict__ bh,
    float* __restrict__ qk, int chunk_row0) {
  __shared__ float As[BK][LDA];
  __shared__ float Bs[BK][LDA];
  const int tid = threadIdx.x;
  const int tx = tid & 15;
  const int ty = tid >> 4;
  const int rl0 = blockIdx.x * BM;  // chunk-local row base
  const int n0 = blockIdx.y * BN;   // output col base (0..511)

  const int l_row = tid >> 2;        // 0..63
  const int l_e = (tid & 3) * 4;     // 0,4,8,12

  const int rg = chunk_row0 + rl0 + l_row;  // global row
  const int cch = rg & 15;
  const int pp = rg >> 4;
  const int ll = pp & 511;
  const int bb = pp >> 9;
  const float* arow = x + ((size_t)(bb * 16 + cch) * 512 + ll) * 256;
  const float* brow = Wqkv + (size_t)(n0 + l_row) * 256;

  float acc[4][4] = {};

  for (int e0 = 0; e0 < 256; e0 += BK) {
    const float4 av = *(const float4*)(arow + e0 + l_e);
    const float4 bv = *(const float4*)(brow + e0 + l_e);
    __syncthreads();
    As[l_e + 0][l_row] = av.x;
    As[l_e + 1][l_row] = av.y;
    As[l_e + 2][l_row] = av.z;
    As[l_e + 3][l_row] = av.w;
    Bs[l_e + 0][l_row] = bv.x;
    Bs[l_e + 1][l_row] = bv.y;
    Bs[l_e + 2][l_row] = bv.z;
    Bs[l_e + 3][l_row] = bv.w;
    __syncthreads();
#pragma unroll
    for (int e = 0; e < BK; ++e) {
      const float4 a = *(const float4*)&As[e][ty * 4];
      const float4 b = *(const float4*)&Bs[e][tx * 4];
      acc[0][0] = fmaf(a.x, b.x, acc[0][0]);
      acc[0][1] = fmaf(a.x, b.y, acc[0][1]);
      acc[0][2] = fmaf(a.x, b.z, acc[0][2]);
      acc[0][3] = fmaf(a.x, b.w, acc[0][3]);
      acc[1][0] = fmaf(a.y, b.x, acc[1][0]);
      acc[1][1] = fmaf(a.y, b.y, acc[1][1]);
      acc[1][2] = fmaf(a.y, b.z, acc[1][2]);
      acc[1][3] = fmaf(a.y, b.w, acc[1][3]);
      acc[2][0] = fmaf(a.z, b.x, acc[2][0]);
      acc[2][1] = fmaf(a.z, b.y, acc[2][1]);
      acc[2][2] = fmaf(a.z, b.z, acc[2][2]);
      acc[2][3] = fmaf(a.z, b.w, acc[2][3]);
      acc[3][0] = fmaf(a.w, b.x, acc[3][0]);
      acc[3][1] = fmaf(a.w, b.y, acc[3][1]);
      acc[3][2] = fmaf(a.w, b.z, acc[3][2]);
      acc[3][3] = fmaf(a.w, b.w, acc[3][3]);
    }
  }

  const bool isq = (n0 < 256);  // whole 64-wide tile is q or k
#pragma unroll
  for (int i = 0; i < 4; ++i) {
    const int rl = rl0 + ty * 4 + i;
    const int n = n0 + tx * 4;
    float4 o;
    o.x = acc[i][0] + bqkv[n + 0] + (isq ? bh[n + 0] : 0.f);
    o.y = acc[i][1] + bqkv[n + 1] + (isq ? bh[n + 1] : 0.f);
    o.z = acc[i][2] + bqkv[n + 2] + (isq ? bh[n + 2] : 0.f);
    o.w = acc[i][3] + bqkv[n + 3] + (isq ? bh[n + 3] : 0.f);
    *(float4*)(qk + (size_t)rl * 512 + n) = o;
  }
}

// ---- scores + softmax diagonal: one block per position ----
__global__ __launch_bounds__(256) void ca_score_kernel(
    const float* __restrict__ qk, const float* __restrict__ Vw,
    const float* __restrict__ Vb, const float* __restrict__ ba,
    float* __restrict__ a_buf, int pos0) {
  __shared__ float qs[16][260];  // pad 260: k-reads 2-way aliasing max (free)
  __shared__ float ks[16][260];
  __shared__ float vw_s[256];
  const int tid = threadIdx.x;
  const float* src = qk + (size_t)blockIdx.x * 8192;  // 16 rows x 512
#pragma unroll
  for (int it = 0; it < 32; ++it) {
    const int idx = tid + it * 256;
    const int row = idx >> 9, col = idx & 511;
    const float v = src[idx];
    if (col < 256) qs[row][col] = v;
    else ks[row][col - 256] = v;
  }
  vw_s[tid] = Vw[tid];
  __syncthreads();
  const int qc = tid >> 4, kc = tid & 15;
  float s = 0.f;
  for (int d = 0; d < 256; ++d) {
    const float h = tanh_fast(qs[qc][d] + ks[kc][d]);  // bh already folded into q
    s = fmaf(vw_s[d], h, s);
  }
  s += Vb[0] + ba[0];
  float m = s;
  for (int off = 8; off; off >>= 1) m = fmaxf(m, __shfl_xor(m, off, 16));
  const float e = __expf(s - m);
  float sum = e;
  for (int off = 8; off; off >>= 1) sum += __shfl_xor(sum, off, 16);
  if (kc == qc) a_buf[(size_t)(pos0 + blockIdx.x) * 16 + qc] = e / sum;
}

// ---- out GEMM: y[r,n] = sum_e xf[r,e]*Wcomb[n,e]; out = a*(y+bcomb)+bout ----
__global__ __launch_bounds__(256) void ca_out_gemm_kernel(
    const float* __restrict__ x, const float* __restrict__ Wcomb,
    const float* __restrict__ bcomb, const float* __restrict__ bout,
    const float* __restrict__ a_buf, float* __restrict__ out) {
  __shared__ float As[BK][LDA];
  __shared__ float Bs[BK][LDA];
  const int tid = threadIdx.x;
  const int tx = tid & 15;
  const int ty = tid >> 4;
  const int r0 = blockIdx.x * BM;
  const int n0 = blockIdx.y * BN;

  const int l_row = tid >> 2;
  const int l_e = (tid & 3) * 4;

  const int rg = r0 + l_row;
  const int cch = rg & 15;
  const int pp = rg >> 4;
  const int ll = pp & 511;
  const int bb = pp >> 9;
  const float* arow = x + ((size_t)(bb * 16 + cch) * 512 + ll) * 256;
  const float* brow = Wcomb + (size_t)(n0 + l_row) * 256;

  float acc[4][4] = {};

  for (int e0 = 0; e0 < 256; e0 += BK) {
    const float4 av = *(const float4*)(arow + e0 + l_e);
    const float4 bv = *(const float4*)(brow + e0 + l_e);
    __syncthreads();
    As[l_e + 0][l_row] = av.x;
    As[l_e + 1][l_row] = av.y;
    As[l_e + 2][l_row] = av.z;
    As[l_e + 3][l_row] = av.w;
    Bs[l_e + 0][l_row] = bv.x;
    Bs[l_e + 1][l_row] = bv.y;
    Bs[l_e + 2][l_row] = bv.z;
    Bs[l_e + 3][l_row] = bv.w;
    __syncthreads();
#pragma unroll
    for (int e = 0; e < BK; ++e) {
      const float4 a = *(const float4*)&As[e][ty * 4];
      const float4 b = *(const float4*)&Bs[e][tx * 4];
      acc[0][0] = fmaf(a.x, b.x, acc[0][0]);
      acc[0][1] = fmaf(a.x, b.y, acc[0][1]);
      acc[0][2] = fmaf(a.x, b.z, acc[0][2]);
      acc[0][3] = fmaf(a.x, b.w, acc[0][3]);
      acc[1][0] = fmaf(a.y, b.x, acc[1][0]);
      acc[1][1] = fmaf(a.y, b.y, acc[1][1]);
      acc[1][2] = fmaf(a.y, b.z, acc[1][2]);
      acc[1][3] = fmaf(a.y, b.w, acc[1][3]);
      acc[2][0] = fmaf(a.z, b.x, acc[2][0]);
      acc[2][1] = fmaf(a.z, b.y, acc[2][1]);
      acc[2][2] = fmaf(a.z, b.z, acc[2][2]);
      acc[2][3] = fmaf(a.z, b.w, acc[2][3]);
      acc[3][0] = fmaf(a.w, b.x, acc[3][0]);
      acc[3][1] = fmaf(a.w, b.y, acc[3][1]);
      acc[3][2] = fmaf(a.w, b.z, acc[3][2]);
      acc[3][3] = fmaf(a.w, b.w, acc[3][3]);
    }
  }

#pragma unroll
  for (int i = 0; i < 4; ++i) {
    const int r = r0 + ty * 4 + i;
    const int c = r & 15;
    const int p = r >> 4;
    const int l = p & 511;
    const int b = p >> 9;
    const float av = a_buf[r];
    const int n = n0 + tx * 4;
    float4 o;
    o.x = fmaf(av, acc[i][0] + bcomb[n + 0], bout[n + 0]);
    o.y = fmaf(av, acc[i][1] + bcomb[n + 1], bout[n + 1]);
    o.z = fmaf(av, acc[i][2] + bcomb[n + 2], bout[n + 2]);
    o.w = fmaf(av, acc[i][3] + bcomb[n + 3], bout[n + 3]);
    *(float4*)(out + ((size_t)(b * 16 + c) * 512 + l) * 256 + n) = o;
  }
}

extern "C" void kernel_launch(void* const* d_in, const int* in_sizes, int n_in,
                              void* d_out, int out_size, void* d_ws, size_t ws_size,
                              hipStream_t stream) {
  (void)in_sizes; (void)n_in; (void)out_size;
  const float* x    = (const float*)d_in[0];
  const float* Wqkv = (const float*)d_in[1];
  const float* bqkv = (const float*)d_in[2];
  const float* Vw   = (const float*)d_in[3];
  const float* Vb   = (const float*)d_in[4];
  const float* bh   = (const float*)d_in[5];
  const float* ba   = (const float*)d_in[6];
  const float* Wout = (const float*)d_in[7];
  const float* bout = (const float*)d_in[8];
  float* out = (float*)d_out;

  // ws layout: a_buf (65536 f) | Wcomb (65536 f) | bcomb (256 f) | qk chunk buf
  float* a_buf = (float*)d_ws;
  float* Wcomb = a_buf + 65536;
  float* bcomb = Wcomb + 65536;
  float* qkbuf = bcomb + 256;
  const size_t fixed_bytes = (size_t)(65536 + 65536 + 256) * 4;

  // Choose the largest q/k chunk that fits in ws (chunk over positions).
  int chunks = 1;
  while (chunks < 1024 &&
         fixed_bytes + (size_t)(65536 / chunks) * 512 * 4 > ws_size)
    chunks *= 2;

  const int rows_pc = 65536 / chunks;  // multiple of 64
  const int pos_pc = rows_pc / 16;

  ca_prep_kernel<<<dim3(256), dim3(256), 0, stream>>>(Wqkv, Wout, bqkv, Wcomb, bcomb);
  for (int ch = 0; ch < chunks; ++ch) {
    const int row0 = ch * rows_pc;
    ca_qk_gemm_kernel<<<dim3(rows_pc / 64, 8), dim3(256), 0, stream>>>(
        x, Wqkv, bqkv, bh, qkbuf, row0);
    ca_score_kernel<<<dim3(pos_pc), dim3(256), 0, stream>>>(
        qkbuf, Vw, Vb, ba, a_buf, row0 / 16);
  }
  ca_out_gemm_kernel<<<dim3(1024, 4), dim3(256), 0, stream>>>(
      x, Wcomb, bcomb, bout, a_buf, out);
}

// Round 2
// 309.055 us; speedup vs baseline: 1.7914x; 1.7914x over previous
//
#include <hip/hip_runtime.h>

// cAttention B=8, C=16, L=512, D=256 (fp32 in/out).
// R2: both GEMMs moved to bf16 MFMA (16x16x32), m97-style 128x128 tiles with
// global_load_lds width-16 staging. qk buffer kept fp32 for precision margin.
//
// Pipeline:
//   prep:      Wcomb = Wout@Wv -> bf16, bcomb = Wout@bv (fp32)
//   convert:   x -> xb (bf16, xf row layout r=((b*512+l)*16+c)), Wqkv -> bf16
//   qk MFMA:   qk[r,0:512] = xb @ Wqkv_b^T + bqkv (+bh on q half), fp32 out
//   score:     s[q,k] = sum_d Vw[d]*tanh(q_d+k_d); a = softmax diagonal
//   out MFMA:  out = a * (xb @ Wcomb_b^T + bcomb) + bout, permuted to (b,c,l,d)

typedef __attribute__((ext_vector_type(8))) short bf16x8;
typedef __attribute__((ext_vector_type(4))) float f32x4;
typedef const __attribute__((address_space(1))) void* gp1_t;
typedef __attribute__((address_space(3))) void* lp3_t;

__device__ __forceinline__ unsigned short f2bf(float f) {
  union { float f; unsigned int u; } v; v.f = f;
  return (unsigned short)((v.u + 0x7FFFu + ((v.u >> 16) & 1u)) >> 16);
}

__device__ __forceinline__ float tanh_fast(float x) {
  x = fminf(10.f, fmaxf(-10.f, x));
  const float e2 = __expf(2.f * x);
  return (e2 - 1.f) * __builtin_amdgcn_rcpf(e2 + 1.f);
}

// ---- prep: Wcomb(bf16) = Wout @ Wv, bcomb(fp32) = Wout @ bv ----
__global__ __launch_bounds__(256) void ca_prep_kernel(
    const float* __restrict__ Wqkv, const float* __restrict__ Wout,
    const float* __restrict__ bqkv,
    unsigned short* __restrict__ Wcomb_b, float* __restrict__ bcomb) {
  const int dp = blockIdx.x;
  const int e = threadIdx.x;
  const float* wrow = Wout + (size_t)dp * 256;
  float acc = 0.f;
  for (int f = 0; f < 256; ++f)
    acc = fmaf(wrow[f], Wqkv[(size_t)(512 + f) * 256 + e], acc);
  Wcomb_b[(size_t)dp * 256 + e] = f2bf(acc);
  if (e == 0) {
    float b = 0.f;
    for (int f = 0; f < 256; ++f) b = fmaf(wrow[f], bqkv[512 + f], b);
    bcomb[dp] = b;
  }
}

// ---- convert Wqkv -> bf16 (512x256) ----
__global__ __launch_bounds__(256) void ca_convert_w(
    const float* __restrict__ W, unsigned short* __restrict__ Wb) {
  const int i = blockIdx.x * 256 + threadIdx.x;
  Wb[i] = f2bf(W[i]);
}

// ---- convert x (b,c,l,d) fp32 -> xb[r][d] bf16, r = ((b*512+l)*16+c) ----
__global__ __launch_bounds__(256) void ca_convert_x(
    const float* __restrict__ x, unsigned short* __restrict__ xb) {
  const size_t t = (size_t)blockIdx.x * 256 + threadIdx.x;
  const size_t E = t * 8;
  const int d = (int)(E & 255);
  const int rin = (int)(E >> 8);             // row in (b,c,l) order
  const int b = rin >> 13, c = (rin >> 9) & 15, l = rin & 511;
  const int rout = ((b << 9 | l) << 4) | c;  // (b*512+l)*16+c
  const float4 v0 = *(const float4*)(x + E);
  const float4 v1 = *(const float4*)(x + E + 4);
  bf16x8 o;
  o[0] = (short)f2bf(v0.x); o[1] = (short)f2bf(v0.y);
  o[2] = (short)f2bf(v0.z); o[3] = (short)f2bf(v0.w);
  o[4] = (short)f2bf(v1.x); o[5] = (short)f2bf(v1.y);
  o[6] = (short)f2bf(v1.z); o[7] = (short)f2bf(v1.w);
  *(bf16x8*)(xb + (size_t)rout * 256 + d) = o;
}

// ---- MFMA mainloop (shared shape): 128x128 tile, BK=32, K=256 ----
// LDS: A/B tiles 128 rows x 32 cols bf16, row-major contiguous (64 B/row).
// Staging: seg s in [0,512): row=s>>2, colseg=s&3; LDS addr = s*16 B.
// Wave w issues segs [w*128, w*128+128) as 2 global_load_lds (64 lanes x 16 B).

#define MFMA_MAIN(XB_PTR, WB_PTR, RT0, N0)                                     \
  __shared__ unsigned short As[128 * 32];                                      \
  __shared__ unsigned short Bs[128 * 32];                                      \
  const int tid = threadIdx.x;                                                 \
  const int lane = tid & 63, wave = tid >> 6;                                  \
  const int wm = wave & 1, wn = wave >> 1;                                     \
  const int s0 = wave * 128 + lane;                                            \
  const int s1 = s0 + 64;                                                      \
  const unsigned short* ga0 = (XB_PTR) + (size_t)((RT0) + (s0 >> 2)) * 256 + (s0 & 3) * 8; \
  const unsigned short* ga1 = (XB_PTR) + (size_t)((RT0) + (s1 >> 2)) * 256 + (s1 & 3) * 8; \
  const unsigned short* gb0 = (WB_PTR) + (size_t)((N0) + (s0 >> 2)) * 256 + (s0 & 3) * 8;  \
  const unsigned short* gb1 = (WB_PTR) + (size_t)((N0) + (s1 >> 2)) * 256 + (s1 & 3) * 8;  \
  unsigned short* lA0 = &As[(wave * 128) * 8];                                 \
  unsigned short* lA1 = &As[(wave * 128 + 64) * 8];                            \
  unsigned short* lB0 = &Bs[(wave * 128) * 8];                                 \
  unsigned short* lB1 = &Bs[(wave * 128 + 64) * 8];                            \
  const int k8 = (lane >> 4) * 8;                                              \
  f32x4 acc[4][4] = {};                                                        \
  for (int e0 = 0; e0 < 256; e0 += 32) {                                       \
    __builtin_amdgcn_global_load_lds((gp1_t)(ga0 + e0), (lp3_t)lA0, 16, 0, 0); \
    __builtin_amdgcn_global_load_lds((gp1_t)(ga1 + e0), (lp3_t)lA1, 16, 0, 0); \
    __builtin_amdgcn_global_load_lds((gp1_t)(gb0 + e0), (lp3_t)lB0, 16, 0, 0); \
    __builtin_amdgcn_global_load_lds((gp1_t)(gb1 + e0), (lp3_t)lB1, 16, 0, 0); \
    __syncthreads();                                                           \
    bf16x8 af[4], bf[4];                                                       \
    _Pragma("unroll")                                                          \
    for (int mi = 0; mi < 4; ++mi)                                             \
      af[mi] = *(const bf16x8*)&As[(wm * 64 + mi * 16 + (lane & 15)) * 32 + k8]; \
    _Pragma("unroll")                                                          \
    for (int ni = 0; ni < 4; ++ni)                                             \
      bf[ni] = *(const bf16x8*)&Bs[(wn * 64 + ni * 16 + (lane & 15)) * 32 + k8]; \
    _Pragma("unroll")                                                          \
    for (int mi = 0; mi < 4; ++mi)                                             \
      _Pragma("unroll")                                                        \
      for (int ni = 0; ni < 4; ++ni)                                           \
        acc[mi][ni] = __builtin_amdgcn_mfma_f32_16x16x32_bf16(                 \
            af[mi], bf[ni], acc[mi][ni], 0, 0, 0);                             \
    __syncthreads();                                                           \
  }

// ---- qk GEMM: qk[rl, n] fp32, n in [0,512); bias folded ----
__global__ __launch_bounds__(256) void ca_qk_mfma(
    const unsigned short* __restrict__ xb, const unsigned short* __restrict__ Wb,
    const float* __restrict__ bqkv, const float* __restrict__ bh,
    float* __restrict__ qk, int row0) {
  const int rt0 = row0 + blockIdx.x * 128;   // global row base (for xb)
  const int n0 = blockIdx.y * 128;
  MFMA_MAIN(xb, Wb, rt0, n0)
  const bool isq = (n0 < 256);
  const int rl0 = blockIdx.x * 128;          // chunk-local row base (for qk)
#pragma unroll
  for (int mi = 0; mi < 4; ++mi) {
#pragma unroll
    for (int ni = 0; ni < 4; ++ni) {
      const int n = n0 + wn * 64 + ni * 16 + (lane & 15);
      const float bias = bqkv[n] + (isq ? bh[n] : 0.f);
      const int rb = rl0 + wm * 64 + mi * 16 + (lane >> 4) * 4;
#pragma unroll
      for (int i2 = 0; i2 < 4; ++i2)
        qk[(size_t)(rb + i2) * 512 + n] = acc[mi][ni][i2] + bias;
    }
  }
}

// ---- out GEMM: out = a * (xb@Wcomb^T + bcomb) + bout, permute to (b,c,l,d) ----
__global__ __launch_bounds__(256) void ca_out_mfma(
    const unsigned short* __restrict__ xb, const unsigned short* __restrict__ Wb,
    const float* __restrict__ bcomb, const float* __restrict__ bout,
    const float* __restrict__ a_buf, float* __restrict__ out) {
  const int rt0 = blockIdx.x * 128;
  const int n0 = blockIdx.y * 128;
  MFMA_MAIN(xb, Wb, rt0, n0)
#pragma unroll
  for (int mi = 0; mi < 4; ++mi) {
#pragma unroll
    for (int ni = 0; ni < 4; ++ni) {
      const int n = n0 + wn * 64 + ni * 16 + (lane & 15);
      const float bc = bcomb[n], bo = bout[n];
      const int rb = rt0 + wm * 64 + mi * 16 + (lane >> 4) * 4;
#pragma unroll
      for (int i2 = 0; i2 < 4; ++i2) {
        const int r = rb + i2;
        const int c = r & 15, p = r >> 4;
        const int l = p & 511, b = p >> 9;
        out[((size_t)(b * 16 + c) * 512 + l) * 256 + n] =
            fmaf(a_buf[r], acc[mi][ni][i2] + bc, bo);
      }
    }
  }
}

// ---- scores + softmax diagonal: one block per position (16 channels) ----
__global__ __launch_bounds__(256) void ca_score_kernel(
    const float* __restrict__ qk, const float* __restrict__ Vw,
    const float* __restrict__ Vb, const float* __restrict__ ba,
    float* __restrict__ a_buf, int pos0) {
  __shared__ float qs[16][260];
  __shared__ float ks[16][260];
  __shared__ float vw_s[256];
  const int tid = threadIdx.x;
  const float* src = qk + (size_t)blockIdx.x * 8192;
#pragma unroll
  for (int it = 0; it < 32; ++it) {
    const int idx = tid + it * 256;
    const int row = idx >> 9, col = idx & 511;
    const float v = src[idx];
    if (col < 256) qs[row][col] = v;
    else ks[row][col - 256] = v;
  }
  vw_s[tid] = Vw[tid];
  __syncthreads();
  const int qc = tid >> 4, kc = tid & 15;
  float s = 0.f;
  for (int d = 0; d < 256; ++d) {
    const float h = tanh_fast(qs[qc][d] + ks[kc][d]);
    s = fmaf(vw_s[d], h, s);
  }
  s += Vb[0] + ba[0];
  float m = s;
  for (int off = 8; off; off >>= 1) m = fmaxf(m, __shfl_xor(m, off, 16));
  const float e = __expf(s - m);
  float sum = e;
  for (int off = 8; off; off >>= 1) sum += __shfl_xor(sum, off, 16);
  if (kc == qc) a_buf[(size_t)(pos0 + blockIdx.x) * 16 + qc] = e / sum;
}

extern "C" void kernel_launch(void* const* d_in, const int* in_sizes, int n_in,
                              void* d_out, int out_size, void* d_ws, size_t ws_size,
                              hipStream_t stream) {
  (void)in_sizes; (void)n_in; (void)out_size;
  const float* x    = (const float*)d_in[0];
  const float* Wqkv = (const float*)d_in[1];
  const float* bqkv = (const float*)d_in[2];
  const float* Vw   = (const float*)d_in[3];
  const float* Vb   = (const float*)d_in[4];
  const float* bh   = (const float*)d_in[5];
  const float* ba   = (const float*)d_in[6];
  const float* Wout = (const float*)d_in[7];
  const float* bout = (const float*)d_in[8];
  float* out = (float*)d_out;

  // ws layout (16B-aligned throughout):
  //   a_buf  fp32 65536            (256 KB)
  //   bcomb  fp32 256              (1 KB)
  //   xb     bf16 65536*256        (33.5 MB)
  //   Wqkv_b bf16 512*256          (256 KB)
  //   Wcomb_b bf16 256*256         (128 KB)
  //   qk     fp32 (65536/chunks)*512
  float* a_buf = (float*)d_ws;
  float* bcomb = a_buf + 65536;
  unsigned short* xb = (unsigned short*)(bcomb + 256);
  unsigned short* Wqkv_b = xb + (size_t)65536 * 256;
  unsigned short* Wcomb_b = Wqkv_b + 512 * 256;
  float* qkbuf = (float*)(Wcomb_b + 256 * 256);
  const size_t fixed_bytes = (size_t)((65536 + 256) * 4) +
                             (size_t)(65536 * 256 + 512 * 256 + 256 * 256) * 2;

  int chunks = 1;
  while (chunks < 512 &&
         fixed_bytes + ((size_t)65536 / chunks) * 512 * 4 > ws_size)
    chunks *= 2;
  const int rows_pc = 65536 / chunks;  // multiple of 128
  const int pos_pc = rows_pc / 16;

  ca_prep_kernel<<<dim3(256), dim3(256), 0, stream>>>(Wqkv, Wout, bqkv, Wcomb_b, bcomb);
  ca_convert_w<<<dim3(512), dim3(256), 0, stream>>>(Wqkv, Wqkv_b);
  ca_convert_x<<<dim3(8192), dim3(256), 0, stream>>>(x, xb);

  for (int ch = 0; ch < chunks; ++ch) {
    const int row0 = ch * rows_pc;
    ca_qk_mfma<<<dim3(rows_pc / 128, 4), dim3(256), 0, stream>>>(
        xb, Wqkv_b, bqkv, bh, qkbuf, row0);
    ca_score_kernel<<<dim3(pos_pc), dim3(256), 0, stream>>>(
        qkbuf, Vw, Vb, ba, a_buf, row0 / 16);
  }
  ca_out_mfma<<<dim3(512, 2), dim3(256), 0, stream>>>(
      xb, Wcomb_b, bcomb, bout, a_buf, out);
}

// Round 3
// 260.737 us; speedup vs baseline: 2.1234x; 1.1853x over previous
//
#include <hip/hip_runtime.h>

// cAttention B=8, C=16, L=512, D=256 (fp32 in/out).
// R3: score phase rewritten:
//   - tanh(x) = 1 - 2/(1+e^{2x}); softmax-invariant constants (SumVw, Vb, ba)
//     dropped; score t = sum_d (-2Vw_d) * rcp(1 + exp2(q'_d + k'_d))
//   - q',k' pre-scaled by 2*log2(e) in the qk epilogue, stored as f16
//     (halves qk traffic -> single chunk fits ws)
//   - float4 LDS reads, 5-inst inner loop (2 transcendentals)

typedef __attribute__((ext_vector_type(8))) short bf16x8;
typedef __attribute__((ext_vector_type(4))) float f32x4;
typedef const __attribute__((address_space(1))) void* gp1_t;
typedef __attribute__((address_space(3))) void* lp3_t;

__device__ __forceinline__ unsigned short f2bf(float f) {
  union { float f; unsigned int u; } v; v.f = f;
  return (unsigned short)((v.u + 0x7FFFu + ((v.u >> 16) & 1u)) >> 16);
}

// ---- prep: Wcomb(bf16) = Wout @ Wv, bcomb(fp32) = Wout @ bv ----
__global__ __launch_bounds__(256) void ca_prep_kernel(
    const float* __restrict__ Wqkv, const float* __restrict__ Wout,
    const float* __restrict__ bqkv,
    unsigned short* __restrict__ Wcomb_b, float* __restrict__ bcomb) {
  const int dp = blockIdx.x;
  const int e = threadIdx.x;
  const float* wrow = Wout + (size_t)dp * 256;
  float acc = 0.f;
  for (int f = 0; f < 256; ++f)
    acc = fmaf(wrow[f], Wqkv[(size_t)(512 + f) * 256 + e], acc);
  Wcomb_b[(size_t)dp * 256 + e] = f2bf(acc);
  if (e == 0) {
    float b = 0.f;
    for (int f = 0; f < 256; ++f) b = fmaf(wrow[f], bqkv[512 + f], b);
    bcomb[dp] = b;
  }
}

// ---- convert Wqkv -> bf16 (512x256) ----
__global__ __launch_bounds__(256) void ca_convert_w(
    const float* __restrict__ W, unsigned short* __restrict__ Wb) {
  const int i = blockIdx.x * 256 + threadIdx.x;
  Wb[i] = f2bf(W[i]);
}

// ---- convert x (b,c,l,d) fp32 -> xb[r][d] bf16, r = ((b*512+l)*16+c) ----
__global__ __launch_bounds__(256) void ca_convert_x(
    const float* __restrict__ x, unsigned short* __restrict__ xb) {
  const size_t t = (size_t)blockIdx.x * 256 + threadIdx.x;
  const size_t E = t * 8;
  const int d = (int)(E & 255);
  const int rin = (int)(E >> 8);
  const int b = rin >> 13, c = (rin >> 9) & 15, l = rin & 511;
  const int rout = ((b << 9 | l) << 4) | c;
  const float4 v0 = *(const float4*)(x + E);
  const float4 v1 = *(const float4*)(x + E + 4);
  bf16x8 o;
  o[0] = (short)f2bf(v0.x); o[1] = (short)f2bf(v0.y);
  o[2] = (short)f2bf(v0.z); o[3] = (short)f2bf(v0.w);
  o[4] = (short)f2bf(v1.x); o[5] = (short)f2bf(v1.y);
  o[6] = (short)f2bf(v1.z); o[7] = (short)f2bf(v1.w);
  *(bf16x8*)(xb + (size_t)rout * 256 + d) = o;
}

// ---- MFMA mainloop: 128x128 tile, BK=32, K=256 ----
#define MFMA_MAIN(XB_PTR, WB_PTR, RT0, N0)                                     \
  __shared__ unsigned short As[128 * 32];                                      \
  __shared__ unsigned short Bs[128 * 32];                                      \
  const int tid = threadIdx.x;                                                 \
  const int lane = tid & 63, wave = tid >> 6;                                  \
  const int wm = wave & 1, wn = wave >> 1;                                     \
  const int s0 = wave * 128 + lane;                                            \
  const int s1 = s0 + 64;                                                      \
  const unsigned short* ga0 = (XB_PTR) + (size_t)((RT0) + (s0 >> 2)) * 256 + (s0 & 3) * 8; \
  const unsigned short* ga1 = (XB_PTR) + (size_t)((RT0) + (s1 >> 2)) * 256 + (s1 & 3) * 8; \
  const unsigned short* gb0 = (WB_PTR) + (size_t)((N0) + (s0 >> 2)) * 256 + (s0 & 3) * 8;  \
  const unsigned short* gb1 = (WB_PTR) + (size_t)((N0) + (s1 >> 2)) * 256 + (s1 & 3) * 8;  \
  unsigned short* lA0 = &As[(wave * 128) * 8];                                 \
  unsigned short* lA1 = &As[(wave * 128 + 64) * 8];                            \
  unsigned short* lB0 = &Bs[(wave * 128) * 8];                                 \
  unsigned short* lB1 = &Bs[(wave * 128 + 64) * 8];                            \
  const int k8 = (lane >> 4) * 8;                                              \
  f32x4 acc[4][4] = {};                                                        \
  for (int e0 = 0; e0 < 256; e0 += 32) {                                       \
    __builtin_amdgcn_global_load_lds((gp1_t)(ga0 + e0), (lp3_t)lA0, 16, 0, 0); \
    __builtin_amdgcn_global_load_lds((gp1_t)(ga1 + e0), (lp3_t)lA1, 16, 0, 0); \
    __builtin_amdgcn_global_load_lds((gp1_t)(gb0 + e0), (lp3_t)lB0, 16, 0, 0); \
    __builtin_amdgcn_global_load_lds((gp1_t)(gb1 + e0), (lp3_t)lB1, 16, 0, 0); \
    __syncthreads();                                                           \
    bf16x8 af[4], bfr[4];                                                      \
    _Pragma("unroll")                                                          \
    for (int mi = 0; mi < 4; ++mi)                                             \
      af[mi] = *(const bf16x8*)&As[(wm * 64 + mi * 16 + (lane & 15)) * 32 + k8]; \
    _Pragma("unroll")                                                          \
    for (int ni = 0; ni < 4; ++ni)                                             \
      bfr[ni] = *(const bf16x8*)&Bs[(wn * 64 + ni * 16 + (lane & 15)) * 32 + k8]; \
    _Pragma("unroll")                                                          \
    for (int mi = 0; mi < 4; ++mi)                                             \
      _Pragma("unroll")                                                        \
      for (int ni = 0; ni < 4; ++ni)                                           \
        acc[mi][ni] = __builtin_amdgcn_mfma_f32_16x16x32_bf16(                 \
            af[mi], bfr[ni], acc[mi][ni], 0, 0, 0);                            \
    __syncthreads();                                                           \
  }

// ---- qk GEMM: qk'[rl, n] = (acc + bias) * 2*log2(e), stored f16 ----
__global__ __launch_bounds__(256) void ca_qk_mfma(
    const unsigned short* __restrict__ xb, const unsigned short* __restrict__ Wb,
    const float* __restrict__ bqkv, const float* __restrict__ bh,
    _Float16* __restrict__ qk, int row0) {
  const int rt0 = row0 + blockIdx.x * 128;
  const int n0 = blockIdx.y * 128;
  MFMA_MAIN(xb, Wb, rt0, n0)
  const bool isq = (n0 < 256);
  const int rl0 = blockIdx.x * 128;
  const float SC = 2.8853900817779268f;  // 2*log2(e)
#pragma unroll
  for (int mi = 0; mi < 4; ++mi) {
#pragma unroll
    for (int ni = 0; ni < 4; ++ni) {
      const int n = n0 + wn * 64 + ni * 16 + (lane & 15);
      const float bias = bqkv[n] + (isq ? bh[n] : 0.f);
      const int rb = rl0 + wm * 64 + mi * 16 + (lane >> 4) * 4;
#pragma unroll
      for (int i2 = 0; i2 < 4; ++i2)
        qk[(size_t)(rb + i2) * 512 + n] = (_Float16)((acc[mi][ni][i2] + bias) * SC);
    }
  }
}

// ---- out GEMM: out = a * (xb@Wcomb^T + bcomb) + bout, permute to (b,c,l,d) ----
__global__ __launch_bounds__(256) void ca_out_mfma(
    const unsigned short* __restrict__ xb, const unsigned short* __restrict__ Wb,
    const float* __restrict__ bcomb, const float* __restrict__ bout,
    const float* __restrict__ a_buf, float* __restrict__ out) {
  const int rt0 = blockIdx.x * 128;
  const int n0 = blockIdx.y * 128;
  MFMA_MAIN(xb, Wb, rt0, n0)
#pragma unroll
  for (int mi = 0; mi < 4; ++mi) {
#pragma unroll
    for (int ni = 0; ni < 4; ++ni) {
      const int n = n0 + wn * 64 + ni * 16 + (lane & 15);
      const float bc = bcomb[n], bo = bout[n];
      const int rb = rt0 + wm * 64 + mi * 16 + (lane >> 4) * 4;
#pragma unroll
      for (int i2 = 0; i2 < 4; ++i2) {
        const int r = rb + i2;
        const int c = r & 15, p = r >> 4;
        const int l = p & 511, b = p >> 9;
        out[((size_t)(b * 16 + c) * 512 + l) * 256 + n] =
            fmaf(a_buf[r], acc[mi][ni][i2] + bc, bo);
      }
    }
  }
}

// ---- scores + softmax diagonal: one block per position ----
// t[q,k] = sum_d (-2Vw_d) * rcp(1 + exp2(q'_d + k'_d)); a = softmax diag.
__global__ __launch_bounds__(256) void ca_score_kernel(
    const _Float16* __restrict__ qk, const float* __restrict__ Vw,
    float* __restrict__ a_buf, int pos0) {
  __shared__ float qs[16][260];
  __shared__ float ks[16][260];
  __shared__ float vw_s[256];
  const int tid = threadIdx.x;
  const _Float16* src = qk + (size_t)blockIdx.x * 8192;
#pragma unroll
  for (int it = 0; it < 32; ++it) {
    const int idx = tid + it * 256;
    const int row = idx >> 9, col = idx & 511;
    const float v = (float)src[idx];
    const int c = col & 255;
    float* dst = (col < 256) ? &qs[row][c] : &ks[row][c];
    *dst = v;
  }
  vw_s[tid] = -2.f * Vw[tid];
  __syncthreads();
  const int qc = tid >> 4, kc = tid & 15;
  const float* qrow = qs[qc];
  const float* krow = ks[kc];
  float acc = 0.f;
#pragma unroll 8
  for (int d = 0; d < 256; d += 4) {
    const float4 qv = *(const float4*)(qrow + d);
    const float4 kv = *(const float4*)(krow + d);
    const float4 wv = *(const float4*)(vw_s + d);
    acc = fmaf(wv.x, __builtin_amdgcn_rcpf(1.f + __builtin_amdgcn_exp2f(qv.x + kv.x)), acc);
    acc = fmaf(wv.y, __builtin_amdgcn_rcpf(1.f + __builtin_amdgcn_exp2f(qv.y + kv.y)), acc);
    acc = fmaf(wv.z, __builtin_amdgcn_rcpf(1.f + __builtin_amdgcn_exp2f(qv.z + kv.z)), acc);
    acc = fmaf(wv.w, __builtin_amdgcn_rcpf(1.f + __builtin_amdgcn_exp2f(qv.w + kv.w)), acc);
  }
  // softmax over kc (width 16); constants dropped (softmax-invariant)
  float m = acc;
  for (int off = 8; off; off >>= 1) m = fmaxf(m, __shfl_xor(m, off, 16));
  const float e = __builtin_amdgcn_exp2f((acc - m) * 1.4426950408889634f);
  float sum = e;
  for (int off = 8; off; off >>= 1) sum += __shfl_xor(sum, off, 16);
  if (kc == qc) a_buf[(size_t)(pos0 + blockIdx.x) * 16 + qc] = e / sum;
}

extern "C" void kernel_launch(void* const* d_in, const int* in_sizes, int n_in,
                              void* d_out, int out_size, void* d_ws, size_t ws_size,
                              hipStream_t stream) {
  (void)in_sizes; (void)n_in; (void)out_size;
  const float* x    = (const float*)d_in[0];
  const float* Wqkv = (const float*)d_in[1];
  const float* bqkv = (const float*)d_in[2];
  const float* Vw   = (const float*)d_in[3];
  const float* bh   = (const float*)d_in[5];
  const float* Wout = (const float*)d_in[7];
  const float* bout = (const float*)d_in[8];
  float* out = (float*)d_out;

  // ws layout:
  //   a_buf fp32 65536 | bcomb fp32 256 | xb bf16 16.7M | Wqkv_b | Wcomb_b |
  //   qk f16 (65536/chunks)*512
  float* a_buf = (float*)d_ws;
  float* bcomb = a_buf + 65536;
  unsigned short* xb = (unsigned short*)(bcomb + 256);
  unsigned short* Wqkv_b = xb + (size_t)65536 * 256;
  unsigned short* Wcomb_b = Wqkv_b + 512 * 256;
  _Float16* qkbuf = (_Float16*)(Wcomb_b + 256 * 256);
  const size_t fixed_bytes = (size_t)((65536 + 256) * 4) +
                             (size_t)(65536 * 256 + 512 * 256 + 256 * 256) * 2;

  int chunks = 1;
  while (chunks < 512 &&
         fixed_bytes + ((size_t)65536 / chunks) * 512 * 2 > ws_size)
    chunks *= 2;
  const int rows_pc = 65536 / chunks;
  const int pos_pc = rows_pc / 16;

  ca_prep_kernel<<<dim3(256), dim3(256), 0, stream>>>(Wqkv, Wout, bqkv, Wcomb_b, bcomb);
  ca_convert_w<<<dim3(512), dim3(256), 0, stream>>>(Wqkv, Wqkv_b);
  ca_convert_x<<<dim3(8192), dim3(256), 0, stream>>>(x, xb);

  for (int ch = 0; ch < chunks; ++ch) {
    const int row0 = ch * rows_pc;
    ca_qk_mfma<<<dim3(rows_pc / 128, 4), dim3(256), 0, stream>>>(
        xb, Wqkv_b, bqkv, bh, qkbuf, row0);
    ca_score_kernel<<<dim3(pos_pc), dim3(256), 0, stream>>>(
        qkbuf, Vw, a_buf, row0 / 16);
  }
  ca_out_mfma<<<dim3(512, 2), dim3(256), 0, stream>>>(
      xb, Wcomb_b, bcomb, bout, a_buf, out);
}

// Round 4
// 258.014 us; speedup vs baseline: 2.1458x; 1.0106x over previous
//
#include <hip/hip_runtime.h>

// cAttention B=8, C=16, L=512, D=256 (fp32 in/out).
// R4:
//   - qk epilogue stores Eq=exp2(clamp(q'*2log2e)) / Ek as f16 -> score loop
//     drops to 1 transcendental (rcp) per element: sum (-2Vw)*rcp(1+Eq*Ek)
//   - MFMA operand swap in both GEMMs: lane's 4 acc elems = 4 consecutive n
//     -> vectorized epilogue stores (f16x4 / float4) instead of 64 scalars
//   - vectorized score staging

typedef __attribute__((ext_vector_type(8))) short bf16x8;
typedef __attribute__((ext_vector_type(4))) float f32x4;
typedef __attribute__((ext_vector_type(8))) _Float16 h16x8;
typedef __attribute__((ext_vector_type(4))) _Float16 h16x4;
typedef const __attribute__((address_space(1))) void* gp1_t;
typedef __attribute__((address_space(3))) void* lp3_t;

__device__ __forceinline__ unsigned short f2bf(float f) {
  union { float f; unsigned int u; } v; v.f = f;
  return (unsigned short)((v.u + 0x7FFFu + ((v.u >> 16) & 1u)) >> 16);
}

// ---- prep: Wcomb(bf16) = Wout @ Wv, bcomb(fp32) = Wout @ bv ----
__global__ __launch_bounds__(256) void ca_prep_kernel(
    const float* __restrict__ Wqkv, const float* __restrict__ Wout,
    const float* __restrict__ bqkv,
    unsigned short* __restrict__ Wcomb_b, float* __restrict__ bcomb) {
  const int dp = blockIdx.x;
  const int e = threadIdx.x;
  const float* wrow = Wout + (size_t)dp * 256;
  float acc = 0.f;
  for (int f = 0; f < 256; ++f)
    acc = fmaf(wrow[f], Wqkv[(size_t)(512 + f) * 256 + e], acc);
  Wcomb_b[(size_t)dp * 256 + e] = f2bf(acc);
  if (e == 0) {
    float b = 0.f;
    for (int f = 0; f < 256; ++f) b = fmaf(wrow[f], bqkv[512 + f], b);
    bcomb[dp] = b;
  }
}

// ---- convert Wqkv -> bf16 (512x256) ----
__global__ __launch_bounds__(256) void ca_convert_w(
    const float* __restrict__ W, unsigned short* __restrict__ Wb) {
  const int i = blockIdx.x * 256 + threadIdx.x;
  Wb[i] = f2bf(W[i]);
}

// ---- convert x (b,c,l,d) fp32 -> xb[r][d] bf16, r = ((b*512+l)*16+c) ----
__global__ __launch_bounds__(256) void ca_convert_x(
    const float* __restrict__ x, unsigned short* __restrict__ xb) {
  const size_t t = (size_t)blockIdx.x * 256 + threadIdx.x;
  const size_t E = t * 8;
  const int d = (int)(E & 255);
  const int rin = (int)(E >> 8);
  const int b = rin >> 13, c = (rin >> 9) & 15, l = rin & 511;
  const int rout = ((b << 9 | l) << 4) | c;
  const float4 v0 = *(const float4*)(x + E);
  const float4 v1 = *(const float4*)(x + E + 4);
  bf16x8 o;
  o[0] = (short)f2bf(v0.x); o[1] = (short)f2bf(v0.y);
  o[2] = (short)f2bf(v0.z); o[3] = (short)f2bf(v0.w);
  o[4] = (short)f2bf(v1.x); o[5] = (short)f2bf(v1.y);
  o[6] = (short)f2bf(v1.z); o[7] = (short)f2bf(v1.w);
  *(bf16x8*)(xb + (size_t)rout * 256 + d) = o;
}

// ---- MFMA mainloop: 128x128 tile, BK=32, K=256, OPERAND-SWAPPED ----
// mfma(bfr[ni], af[mi], acc[mi][ni]):
//   tile row (quad*4+i2) -> n within ni-block; tile col (lane&15) -> r within mi-block
#define MFMA_MAIN(XB_PTR, WB_PTR, RT0, N0)                                     \
  __shared__ unsigned short As[128 * 32];                                      \
  __shared__ unsigned short Bs[128 * 32];                                      \
  const int tid = threadIdx.x;                                                 \
  const int lane = tid & 63, wave = tid >> 6;                                  \
  const int wm = wave & 1, wn = wave >> 1;                                     \
  const int quad = lane >> 4;                                                  \
  const int s0 = wave * 128 + lane;                                            \
  const int s1 = s0 + 64;                                                      \
  const unsigned short* ga0 = (XB_PTR) + (size_t)((RT0) + (s0 >> 2)) * 256 + (s0 & 3) * 8; \
  const unsigned short* ga1 = (XB_PTR) + (size_t)((RT0) + (s1 >> 2)) * 256 + (s1 & 3) * 8; \
  const unsigned short* gb0 = (WB_PTR) + (size_t)((N0) + (s0 >> 2)) * 256 + (s0 & 3) * 8;  \
  const unsigned short* gb1 = (WB_PTR) + (size_t)((N0) + (s1 >> 2)) * 256 + (s1 & 3) * 8;  \
  unsigned short* lA0 = &As[(wave * 128) * 8];                                 \
  unsigned short* lA1 = &As[(wave * 128 + 64) * 8];                            \
  unsigned short* lB0 = &Bs[(wave * 128) * 8];                                 \
  unsigned short* lB1 = &Bs[(wave * 128 + 64) * 8];                            \
  const int k8 = quad * 8;                                                     \
  f32x4 acc[4][4] = {};                                                        \
  for (int e0 = 0; e0 < 256; e0 += 32) {                                       \
    __builtin_amdgcn_global_load_lds((gp1_t)(ga0 + e0), (lp3_t)lA0, 16, 0, 0); \
    __builtin_amdgcn_global_load_lds((gp1_t)(ga1 + e0), (lp3_t)lA1, 16, 0, 0); \
    __builtin_amdgcn_global_load_lds((gp1_t)(gb0 + e0), (lp3_t)lB0, 16, 0, 0); \
    __builtin_amdgcn_global_load_lds((gp1_t)(gb1 + e0), (lp3_t)lB1, 16, 0, 0); \
    __syncthreads();                                                           \
    bf16x8 af[4], bfr[4];                                                      \
    _Pragma("unroll")                                                          \
    for (int mi = 0; mi < 4; ++mi)                                             \
      af[mi] = *(const bf16x8*)&As[(wm * 64 + mi * 16 + (lane & 15)) * 32 + k8]; \
    _Pragma("unroll")                                                          \
    for (int ni = 0; ni < 4; ++ni)                                             \
      bfr[ni] = *(const bf16x8*)&Bs[(wn * 64 + ni * 16 + (lane & 15)) * 32 + k8]; \
    _Pragma("unroll")                                                          \
    for (int mi = 0; mi < 4; ++mi)                                             \
      _Pragma("unroll")                                                        \
      for (int ni = 0; ni < 4; ++ni)                                           \
        acc[mi][ni] = __builtin_amdgcn_mfma_f32_16x16x32_bf16(                 \
            bfr[ni], af[mi], acc[mi][ni], 0, 0, 0);                            \
    __syncthreads();                                                           \
  }

// ---- qk GEMM: E[rl, n] = exp2(clamp((acc+bias)*2log2e, +-15)) stored f16 ----
__global__ __launch_bounds__(256) void ca_qk_mfma(
    const unsigned short* __restrict__ xb, const unsigned short* __restrict__ Wb,
    const float* __restrict__ bqkv, const float* __restrict__ bh,
    _Float16* __restrict__ qk, int row0) {
  const int rt0 = row0 + blockIdx.x * 128;
  const int n0 = blockIdx.y * 128;
  MFMA_MAIN(xb, Wb, rt0, n0)
  const bool isq = (n0 < 256);
  const int rl0 = blockIdx.x * 128;
  const float SC = 2.8853900817779268f;  // 2*log2(e)
#pragma unroll
  for (int mi = 0; mi < 4; ++mi) {
    const int r = rl0 + wm * 64 + mi * 16 + (lane & 15);
#pragma unroll
    for (int ni = 0; ni < 4; ++ni) {
      const int nb = n0 + wn * 64 + ni * 16 + quad * 4;
      const float4 bq = *(const float4*)(bqkv + nb);
      float4 bhv = make_float4(0.f, 0.f, 0.f, 0.f);
      if (isq) bhv = *(const float4*)(bh + nb);
      h16x4 st;
      st[0] = (_Float16)__builtin_amdgcn_exp2f(
          fminf(15.f, fmaxf(-15.f, (acc[mi][ni][0] + bq.x + bhv.x) * SC)));
      st[1] = (_Float16)__builtin_amdgcn_exp2f(
          fminf(15.f, fmaxf(-15.f, (acc[mi][ni][1] + bq.y + bhv.y) * SC)));
      st[2] = (_Float16)__builtin_amdgcn_exp2f(
          fminf(15.f, fmaxf(-15.f, (acc[mi][ni][2] + bq.z + bhv.z) * SC)));
      st[3] = (_Float16)__builtin_amdgcn_exp2f(
          fminf(15.f, fmaxf(-15.f, (acc[mi][ni][3] + bq.w + bhv.w) * SC)));
      *(h16x4*)(qk + (size_t)r * 512 + nb) = st;
    }
  }
}

// ---- out GEMM: out = a * (xb@Wcomb^T + bcomb) + bout, permute to (b,c,l,d) ----
__global__ __launch_bounds__(256) void ca_out_mfma(
    const unsigned short* __restrict__ xb, const unsigned short* __restrict__ Wb,
    const float* __restrict__ bcomb, const float* __restrict__ bout,
    const float* __restrict__ a_buf, float* __restrict__ out) {
  const int rt0 = blockIdx.x * 128;
  const int n0 = blockIdx.y * 128;
  MFMA_MAIN(xb, Wb, rt0, n0)
#pragma unroll
  for (int mi = 0; mi < 4; ++mi) {
    const int r = rt0 + wm * 64 + mi * 16 + (lane & 15);
    const int c = r & 15, p = r >> 4;
    const int l = p & 511, b = p >> 9;
    const float av = a_buf[r];
    float* orow = out + ((size_t)(b * 16 + c) * 512 + l) * 256;
#pragma unroll
    for (int ni = 0; ni < 4; ++ni) {
      const int nb = n0 + wn * 64 + ni * 16 + quad * 4;
      const float4 bc = *(const float4*)(bcomb + nb);
      const float4 bo = *(const float4*)(bout + nb);
      float4 o;
      o.x = fmaf(av, acc[mi][ni][0] + bc.x, bo.x);
      o.y = fmaf(av, acc[mi][ni][1] + bc.y, bo.y);
      o.z = fmaf(av, acc[mi][ni][2] + bc.z, bo.z);
      o.w = fmaf(av, acc[mi][ni][3] + bc.w, bo.w);
      *(float4*)(orow + nb) = o;
    }
  }
}

// ---- scores + softmax diag: t = sum (-2Vw)*rcp(1+Eq*Ek), one block/position ----
__global__ __launch_bounds__(256) void ca_score_kernel(
    const _Float16* __restrict__ qk, const float* __restrict__ Vw,
    float* __restrict__ a_buf, int pos0) {
  __shared__ float qs[16][260];
  __shared__ float ks[16][260];
  __shared__ float vw_s[256];
  const int tid = threadIdx.x;
  const _Float16* src = qk + (size_t)blockIdx.x * 8192;
#pragma unroll
  for (int it = 0; it < 4; ++it) {
    const int seg = tid + it * 256;      // [0,1024): 8 f16 each
    const int row = seg >> 6;
    const int col = (seg & 63) * 8;
    const h16x8 v = *(const h16x8*)(src + (size_t)seg * 8);
    float* dst = (col < 256) ? &qs[row][col] : &ks[row][col - 256];
    float4 w0, w1;
    w0.x = (float)v[0]; w0.y = (float)v[1]; w0.z = (float)v[2]; w0.w = (float)v[3];
    w1.x = (float)v[4]; w1.y = (float)v[5]; w1.z = (float)v[6]; w1.w = (float)v[7];
    ((float4*)dst)[0] = w0;
    ((float4*)dst)[1] = w1;
  }
  vw_s[tid] = -2.f * Vw[tid];
  __syncthreads();
  const int qc = tid >> 4, kc = tid & 15;
  const float* qrow = qs[qc];
  const float* krow = ks[kc];
  f32x4 acc4 = {};
#pragma unroll 4
  for (int d = 0; d < 256; d += 4) {
    const f32x4 eq = *(const f32x4*)(qrow + d);
    const f32x4 ek = *(const f32x4*)(krow + d);
    const f32x4 wv = *(const f32x4*)(vw_s + d);
    const f32x4 pr = eq * ek;           // v_pk_mul_f32
    f32x4 sg;
    sg.x = __builtin_amdgcn_rcpf(1.f + pr.x);
    sg.y = __builtin_amdgcn_rcpf(1.f + pr.y);
    sg.z = __builtin_amdgcn_rcpf(1.f + pr.z);
    sg.w = __builtin_amdgcn_rcpf(1.f + pr.w);
    acc4 += wv * sg;                    // v_pk_fma_f32
  }
  float s = (acc4[0] + acc4[1]) + (acc4[2] + acc4[3]);
  float m = s;
  for (int off = 8; off; off >>= 1) m = fmaxf(m, __shfl_xor(m, off, 16));
  const float e = __builtin_amdgcn_exp2f((s - m) * 1.4426950408889634f);
  float sum = e;
  for (int off = 8; off; off >>= 1) sum += __shfl_xor(sum, off, 16);
  if (kc == qc) a_buf[(size_t)(pos0 + blockIdx.x) * 16 + qc] = e / sum;
}

extern "C" void kernel_launch(void* const* d_in, const int* in_sizes, int n_in,
                              void* d_out, int out_size, void* d_ws, size_t ws_size,
                              hipStream_t stream) {
  (void)in_sizes; (void)n_in; (void)out_size;
  const float* x    = (const float*)d_in[0];
  const float* Wqkv = (const float*)d_in[1];
  const float* bqkv = (const float*)d_in[2];
  const float* Vw   = (const float*)d_in[3];
  const float* bh   = (const float*)d_in[5];
  const float* Wout = (const float*)d_in[7];
  const float* bout = (const float*)d_in[8];
  float* out = (float*)d_out;

  // ws: a_buf fp32 65536 | bcomb fp32 256 | xb bf16 16.7M | Wqkv_b | Wcomb_b |
  //     qk f16 (65536/chunks)*512
  float* a_buf = (float*)d_ws;
  float* bcomb = a_buf + 65536;
  unsigned short* xb = (unsigned short*)(bcomb + 256);
  unsigned short* Wqkv_b = xb + (size_t)65536 * 256;
  unsigned short* Wcomb_b = Wqkv_b + 512 * 256;
  _Float16* qkbuf = (_Float16*)(Wcomb_b + 256 * 256);
  const size_t fixed_bytes = (size_t)((65536 + 256) * 4) +
                             (size_t)(65536 * 256 + 512 * 256 + 256 * 256) * 2;

  int chunks = 1;
  while (chunks < 512 &&
         fixed_bytes + ((size_t)65536 / chunks) * 512 * 2 > ws_size)
    chunks *= 2;
  const int rows_pc = 65536 / chunks;
  const int pos_pc = rows_pc / 16;

  ca_prep_kernel<<<dim3(256), dim3(256), 0, stream>>>(Wqkv, Wout, bqkv, Wcomb_b, bcomb);
  ca_convert_w<<<dim3(512), dim3(256), 0, stream>>>(Wqkv, Wqkv_b);
  ca_convert_x<<<dim3(8192), dim3(256), 0, stream>>>(x, xb);

  for (int ch = 0; ch < chunks; ++ch) {
    const int row0 = ch * rows_pc;
    ca_qk_mfma<<<dim3(rows_pc / 128, 4), dim3(256), 0, stream>>>(
        xb, Wqkv_b, bqkv, bh, qkbuf, row0);
    ca_score_kernel<<<dim3(pos_pc), dim3(256), 0, stream>>>(
        qkbuf, Vw, a_buf, row0 / 16);
  }
  ca_out_mfma<<<dim3(512, 2), dim3(256), 0, stream>>>(
      xb, Wcomb_b, bcomb, bout, a_buf, out);
}

// Round 5
// 229.017 us; speedup vs baseline: 2.4175x; 1.1266x over previous
//
#include <hip/hip_runtime.h>

// cAttention B=8, C=16, L=512, D=256 (fp32 in/out).
// R5: single fused kernel for qk-GEMM + exp + score + softmax-diag + out-GEMM.
// Block = 512 threads (8 waves), 2 positions (32 xf rows), 2048 blocks.
//   stage1: 32x512 MFMA tile (A=xb rows, B=Wqkv), E=exp2(...) -> LDS (32x520 f16)
//   score:  1 score/thread: t = sum (-2Vw) * rcp(1 + Eq*Ek); shfl-16 softmax diag
//   stage2: 32x256 MFMA tile (B=Wcomb), out = a*(acc+bcomb)+bout, float4 stores
// E never touches HBM; stage2 tiles prefetched during the score phase.

typedef __attribute__((ext_vector_type(8))) short bf16x8;
typedef __attribute__((ext_vector_type(4))) float f32x4;
typedef __attribute__((ext_vector_type(8))) _Float16 h16x8;
typedef __attribute__((ext_vector_type(4))) _Float16 h16x4;
typedef const __attribute__((address_space(1))) void* gp1_t;
typedef __attribute__((address_space(3))) void* lp3_t;

__device__ __forceinline__ unsigned short f2bf(float f) {
  union { float f; unsigned int u; } v; v.f = f;
  return (unsigned short)((v.u + 0x7FFFu + ((v.u >> 16) & 1u)) >> 16);
}

// ---- prep: Wcomb(bf16) = Wout @ Wv, bcomb(fp32) = Wout @ bv ----
__global__ __launch_bounds__(256) void ca_prep_kernel(
    const float* __restrict__ Wqkv, const float* __restrict__ Wout,
    const float* __restrict__ bqkv,
    unsigned short* __restrict__ Wcomb_b, float* __restrict__ bcomb) {
  const int dp = blockIdx.x;
  const int e = threadIdx.x;
  const float* wrow = Wout + (size_t)dp * 256;
  float acc = 0.f;
  for (int f = 0; f < 256; ++f)
    acc = fmaf(wrow[f], Wqkv[(size_t)(512 + f) * 256 + e], acc);
  Wcomb_b[(size_t)dp * 256 + e] = f2bf(acc);
  if (e == 0) {
    float b = 0.f;
    for (int f = 0; f < 256; ++f) b = fmaf(wrow[f], bqkv[512 + f], b);
    bcomb[dp] = b;
  }
}

// ---- convert Wqkv -> bf16 (512x256) ----
__global__ __launch_bounds__(256) void ca_convert_w(
    const float* __restrict__ W, unsigned short* __restrict__ Wb) {
  const int i = blockIdx.x * 256 + threadIdx.x;
  Wb[i] = f2bf(W[i]);
}

// ---- convert x (b,c,l,d) fp32 -> xb[r][d] bf16, r = ((b*512+l)*16+c) ----
__global__ __launch_bounds__(256) void ca_convert_x(
    const float* __restrict__ x, unsigned short* __restrict__ xb) {
  const size_t t = (size_t)blockIdx.x * 256 + threadIdx.x;
  const size_t E = t * 8;
  const int d = (int)(E & 255);
  const int rin = (int)(E >> 8);
  const int b = rin >> 13, c = (rin >> 9) & 15, l = rin & 511;
  const int rout = ((b << 9 | l) << 4) | c;
  const float4 v0 = *(const float4*)(x + E);
  const float4 v1 = *(const float4*)(x + E + 4);
  bf16x8 o;
  o[0] = (short)f2bf(v0.x); o[1] = (short)f2bf(v0.y);
  o[2] = (short)f2bf(v0.z); o[3] = (short)f2bf(v0.w);
  o[4] = (short)f2bf(v1.x); o[5] = (short)f2bf(v1.y);
  o[6] = (short)f2bf(v1.z); o[7] = (short)f2bf(v1.w);
  *(bf16x8*)(xb + (size_t)rout * 256 + d) = o;
}

// ---- fused: qk MFMA + exp + score + softmax diag + out MFMA ----
__global__ __launch_bounds__(512) void ca_fused(
    const unsigned short* __restrict__ xb,   // 65536 x 256 bf16
    const unsigned short* __restrict__ Wqb,  // 512 x 256 bf16
    const unsigned short* __restrict__ Wcb,  // 256 x 256 bf16
    const float* __restrict__ bqkv, const float* __restrict__ bh,
    const float* __restrict__ Vw,
    const float* __restrict__ bcomb, const float* __restrict__ bout,
    float* __restrict__ out) {
  __shared__ unsigned short As[32 * 32];    // 2 KB   A tile (32 rows x 32 k)
  __shared__ unsigned short Bs[512 * 32];   // 32 KB  B tile (n-major x 32 k)
  __shared__ _Float16 Es[32 * 520];         // 33.3 KB E (row-stride 520: pad)
  __shared__ float vw_s[256];
  __shared__ float af_s[32];

  const int tid = threadIdx.x;
  const int lane = tid & 63, wave = tid >> 6;
  const int quad = lane >> 4, l15 = lane & 15;
  const int rt0 = blockIdx.x * 32;          // global xf row base

  if (tid < 256) vw_s[tid] = -2.f * Vw[tid];

  // ---------- stage 1: E[32 x 512] ----------
  f32x4 acc[2][4] = {};
  for (int k0 = 0; k0 < 256; k0 += 32) {
    // A: 128 segs (16B each), waves 0-1
    if (wave < 2) {
      const int s = wave * 64 + lane;
      const unsigned short* g =
          xb + (size_t)(rt0 + (s >> 2)) * 256 + k0 + (s & 3) * 8;
      __builtin_amdgcn_global_load_lds((gp1_t)g, (lp3_t)(As + wave * 512), 16, 0, 0);
    }
    // B: 2048 segs, 4 per wave
#pragma unroll
    for (int i = 0; i < 4; ++i) {
      const int sb = wave * 256 + i * 64;
      const int s = sb + lane;
      const unsigned short* g =
          Wqb + (size_t)(s >> 2) * 256 + k0 + (s & 3) * 8;
      __builtin_amdgcn_global_load_lds((gp1_t)g, (lp3_t)(Bs + sb * 8), 16, 0, 0);
    }
    __syncthreads();
    bf16x8 af[2], bfr[4];
#pragma unroll
    for (int mi = 0; mi < 2; ++mi)
      af[mi] = *(const bf16x8*)&As[(mi * 16 + l15) * 32 + quad * 8];
#pragma unroll
    for (int ni = 0; ni < 4; ++ni)
      bfr[ni] = *(const bf16x8*)&Bs[(wave * 64 + ni * 16 + l15) * 32 + quad * 8];
#pragma unroll
    for (int mi = 0; mi < 2; ++mi)
#pragma unroll
      for (int ni = 0; ni < 4; ++ni)
        acc[mi][ni] = __builtin_amdgcn_mfma_f32_16x16x32_bf16(
            bfr[ni], af[mi], acc[mi][ni], 0, 0, 0);
    __syncthreads();
  }

  // stage-1 epilogue: E = exp2(clamp((acc+bias)*2log2e, +-15)) -> LDS
  const float SC = 2.8853900817779268f;  // 2*log2(e)
  const bool isq = (wave < 4);           // n < 256
#pragma unroll
  for (int mi = 0; mi < 2; ++mi) {
    const int rl = mi * 16 + l15;
#pragma unroll
    for (int ni = 0; ni < 4; ++ni) {
      const int n = wave * 64 + ni * 16 + quad * 4;
      const float4 bq = *(const float4*)(bqkv + n);
      float4 bhv = make_float4(0.f, 0.f, 0.f, 0.f);
      if (isq) bhv = *(const float4*)(bh + n);
      h16x4 st;
      st[0] = (_Float16)__builtin_amdgcn_exp2f(
          fminf(15.f, fmaxf(-15.f, (acc[mi][ni][0] + bq.x + bhv.x) * SC)));
      st[1] = (_Float16)__builtin_amdgcn_exp2f(
          fminf(15.f, fmaxf(-15.f, (acc[mi][ni][1] + bq.y + bhv.y) * SC)));
      st[2] = (_Float16)__builtin_amdgcn_exp2f(
          fminf(15.f, fmaxf(-15.f, (acc[mi][ni][2] + bq.z + bhv.z) * SC)));
      st[3] = (_Float16)__builtin_amdgcn_exp2f(
          fminf(15.f, fmaxf(-15.f, (acc[mi][ni][3] + bq.w + bhv.w) * SC)));
      *(h16x4*)&Es[rl * 520 + n] = st;
    }
  }

  // prefetch stage-2 k0=0 tiles into As/Bs (free after stage-1 barrier)
  {
    if (wave < 2) {
      const int s = wave * 64 + lane;
      const unsigned short* g =
          xb + (size_t)(rt0 + (s >> 2)) * 256 + (s & 3) * 8;
      __builtin_amdgcn_global_load_lds((gp1_t)g, (lp3_t)(As + wave * 512), 16, 0, 0);
    }
#pragma unroll
    for (int i = 0; i < 2; ++i) {
      const int sb = wave * 128 + i * 64;
      const int s = sb + lane;
      const unsigned short* g = Wcb + (size_t)(s >> 2) * 256 + (s & 3) * 8;
      __builtin_amdgcn_global_load_lds((gp1_t)g, (lp3_t)(Bs + sb * 8), 16, 0, 0);
    }
  }
  __syncthreads();  // Es ready + prefetch drained

  // ---------- score: 1 score/thread ----------
  {
    const int p = tid >> 8, qc = (tid >> 4) & 15, kc = tid & 15;
    const _Float16* eqp = Es + (p * 16 + qc) * 520;
    const _Float16* ekp = Es + (p * 16 + kc) * 520 + 256;
    f32x4 a4 = {};
#pragma unroll 4
    for (int d = 0; d < 256; d += 8) {
      const h16x8 eq = *(const h16x8*)(eqp + d);
      const h16x8 ek = *(const h16x8*)(ekp + d);
      const f32x4 wv0 = *(const f32x4*)(vw_s + d);
      const f32x4 wv1 = *(const f32x4*)(vw_s + d + 4);
      f32x4 sg0, sg1;
      sg0.x = __builtin_amdgcn_rcpf(1.f + (float)eq[0] * (float)ek[0]);
      sg0.y = __builtin_amdgcn_rcpf(1.f + (float)eq[1] * (float)ek[1]);
      sg0.z = __builtin_amdgcn_rcpf(1.f + (float)eq[2] * (float)ek[2]);
      sg0.w = __builtin_amdgcn_rcpf(1.f + (float)eq[3] * (float)ek[3]);
      sg1.x = __builtin_amdgcn_rcpf(1.f + (float)eq[4] * (float)ek[4]);
      sg1.y = __builtin_amdgcn_rcpf(1.f + (float)eq[5] * (float)ek[5]);
      sg1.z = __builtin_amdgcn_rcpf(1.f + (float)eq[6] * (float)ek[6]);
      sg1.w = __builtin_amdgcn_rcpf(1.f + (float)eq[7] * (float)ek[7]);
      a4 += wv0 * sg0 + wv1 * sg1;
    }
    float s = (a4[0] + a4[1]) + (a4[2] + a4[3]);
    float m = s;
    for (int off = 8; off; off >>= 1) m = fmaxf(m, __shfl_xor(m, off, 16));
    const float e = __builtin_amdgcn_exp2f((s - m) * 1.4426950408889634f);
    float sum = e;
    for (int off = 8; off; off >>= 1) sum += __shfl_xor(sum, off, 16);
    if (kc == qc) af_s[p * 16 + qc] = e / sum;
  }

  // ---------- stage 2: out[32 x 256] ----------
  f32x4 acc2[2][2] = {};
  for (int k0 = 0; k0 < 256; k0 += 32) {
    if (k0) {
      if (wave < 2) {
        const int s = wave * 64 + lane;
        const unsigned short* g =
            xb + (size_t)(rt0 + (s >> 2)) * 256 + k0 + (s & 3) * 8;
        __builtin_amdgcn_global_load_lds((gp1_t)g, (lp3_t)(As + wave * 512), 16, 0, 0);
      }
#pragma unroll
      for (int i = 0; i < 2; ++i) {
        const int sb = wave * 128 + i * 64;
        const int s = sb + lane;
        const unsigned short* g =
            Wcb + (size_t)(s >> 2) * 256 + k0 + (s & 3) * 8;
        __builtin_amdgcn_global_load_lds((gp1_t)g, (lp3_t)(Bs + sb * 8), 16, 0, 0);
      }
    }
    __syncthreads();  // k0==0: also orders af_s writes before epilogue use
    bf16x8 af[2], bfr[2];
#pragma unroll
    for (int mi = 0; mi < 2; ++mi)
      af[mi] = *(const bf16x8*)&As[(mi * 16 + l15) * 32 + quad * 8];
#pragma unroll
    for (int ni = 0; ni < 2; ++ni)
      bfr[ni] = *(const bf16x8*)&Bs[(wave * 32 + ni * 16 + l15) * 32 + quad * 8];
#pragma unroll
    for (int mi = 0; mi < 2; ++mi)
#pragma unroll
      for (int ni = 0; ni < 2; ++ni)
        acc2[mi][ni] = __builtin_amdgcn_mfma_f32_16x16x32_bf16(
            bfr[ni], af[mi], acc2[mi][ni], 0, 0, 0);
    __syncthreads();
  }

  // stage-2 epilogue: out = a*(acc2+bcomb)+bout, permuted (b,c,l,d) store
#pragma unroll
  for (int mi = 0; mi < 2; ++mi) {
    const int rl = mi * 16 + l15;
    const int r = rt0 + rl;
    const int c = r & 15, p = r >> 4;
    const int l = p & 511, b = p >> 9;
    const float av = af_s[rl];
    float* orow = out + ((size_t)(b * 16 + c) * 512 + l) * 256;
#pragma unroll
    for (int ni = 0; ni < 2; ++ni) {
      const int n = wave * 32 + ni * 16 + quad * 4;
      const float4 bc = *(const float4*)(bcomb + n);
      const float4 bo = *(const float4*)(bout + n);
      float4 o;
      o.x = fmaf(av, acc2[mi][ni][0] + bc.x, bo.x);
      o.y = fmaf(av, acc2[mi][ni][1] + bc.y, bo.y);
      o.z = fmaf(av, acc2[mi][ni][2] + bc.z, bo.z);
      o.w = fmaf(av, acc2[mi][ni][3] + bc.w, bo.w);
      *(float4*)(orow + n) = o;
    }
  }
}

extern "C" void kernel_launch(void* const* d_in, const int* in_sizes, int n_in,
                              void* d_out, int out_size, void* d_ws, size_t ws_size,
                              hipStream_t stream) {
  (void)in_sizes; (void)n_in; (void)out_size; (void)ws_size;
  const float* x    = (const float*)d_in[0];
  const float* Wqkv = (const float*)d_in[1];
  const float* bqkv = (const float*)d_in[2];
  const float* Vw   = (const float*)d_in[3];
  const float* bh   = (const float*)d_in[5];
  const float* Wout = (const float*)d_in[7];
  const float* bout = (const float*)d_in[8];
  float* out = (float*)d_out;

  // ws: bcomb fp32 256 | xb bf16 65536*256 | Wqkv_b bf16 512*256 | Wcomb_b bf16 256*256
  float* bcomb = (float*)d_ws;
  unsigned short* xb = (unsigned short*)(bcomb + 256);
  unsigned short* Wqkv_b = xb + (size_t)65536 * 256;
  unsigned short* Wcomb_b = Wqkv_b + 512 * 256;

  ca_prep_kernel<<<dim3(256), dim3(256), 0, stream>>>(Wqkv, Wout, bqkv, Wcomb_b, bcomb);
  ca_convert_w<<<dim3(512), dim3(256), 0, stream>>>(Wqkv, Wqkv_b);
  ca_convert_x<<<dim3(8192), dim3(256), 0, stream>>>(x, xb);
  ca_fused<<<dim3(2048), dim3(512), 0, stream>>>(
      xb, Wqkv_b, Wcomb_b, bqkv, bh, Vw, bcomb, bout, out);
}